// Round 6
// baseline (201.301 us; speedup 1.0000x reference)
//
#include <hip/hip_runtime.h>
#include <math.h>

typedef __bf16 bf16_t;
typedef __bf16 bf16x4 __attribute__((ext_vector_type(4)));
typedef __bf16 bf16x8 __attribute__((ext_vector_type(8)));
typedef float  f32x4  __attribute__((ext_vector_type(4)));
typedef float  f32x8  __attribute__((ext_vector_type(8)));

#define NHEADS 16
#define DH 64
#define SEQ 2048
#define DMODEL 1024

static __device__ __forceinline__ f32x4 mfma_bf16(bf16x8 a, bf16x8 b, f32x4 c) {
  return __builtin_amdgcn_mfma_f32_16x16x32_bf16(a, b, c, 0, 0, 0);
}

// async global->LDS, 16B per lane; LDS dest = wave-uniform base + lane*16
static __device__ __forceinline__ void load_lds16(const bf16_t* g, bf16_t* l) {
  __builtin_amdgcn_global_load_lds(
      (const __attribute__((address_space(1))) void*)g,
      (__attribute__((address_space(3))) void*)l, 16, 0, 0);
}

// ---------------- f32 -> bf16 pre-convert + RoPE table ----------------
// flat dst layout: x(4M) | Wq(1M) | Wk(1M) | Wv(1M) | Wo(1M) elems
// blocks >= 4096 fill tbl[i][s] = (cos, sin)(tpos[s] * theta^(-i/32)),
// i in 0..31, s in 0..2047 -> 512KB, L2-resident for the qkv epilogue.
__global__ __launch_bounds__(256) void convert_kernel(
    const float* __restrict__ x, const float* __restrict__ Wq,
    const float* __restrict__ Wk, const float* __restrict__ Wv,
    const float* __restrict__ Wo, const int* __restrict__ tpos,
    bf16_t* __restrict__ dst, float* __restrict__ tbl)
{
  if (blockIdx.x >= 4096) {
    const int idx2 = (blockIdx.x - 4096) * 256 + threadIdx.x;  // 0..65535
    const int i = idx2 >> 11;          // 0..31
    const int s = idx2 & (SEQ - 1);    // 0..2047
    const float pos  = (float)tpos[s];
    const float freq = expf((float)i * -0.28782313662425573f);
    const float ang  = pos * freq;
    tbl[(size_t)idx2 * 2]     = cosf(ang);
    tbl[(size_t)idx2 * 2 + 1] = sinf(ang);
    return;
  }
  const size_t idx = ((size_t)blockIdx.x * 256 + threadIdx.x) * 8;
  const size_t XN = (size_t)4096 * DMODEL;
  const float* src;
  size_t off;
  if (idx < XN) { src = x; off = idx; }
  else {
    size_t r = idx - XN;
    int q = (int)(r >> 20);
    off = r & ((size_t)(1u << 20) - 1);
    src = (q == 0) ? Wq : (q == 1) ? Wk : (q == 2) ? Wv : Wo;
  }
  f32x8 v = *(const f32x8*)(src + off);
  bf16x8 o;
  #pragma unroll
  for (int j = 0; j < 8; ++j) o[j] = (bf16_t)v[j];
  *(bf16x8*)(dst + idx) = o;
}

// ---------------- shared 128x128 GEMM core, double-buffered ----------------
// v12: LDS double-buffer (attn-style). Per K-step: barrier (tile k DMA
// complete, buf^1 free) -> prefetch tile k+1 into buf^1 -> ds_read+MFMA on
// buf. DMA latency hides under the 16 MFMAs; one barrier per K-step (was 2
// with the load->drain->compute order, which exposed full HBM/L2 latency
// every iteration: qkv MfmaUtil 18%, VALUBusy 10%, HBM 15% -- nothing busy).
// As/Bs are 2x4096 elems each (32KB total).
static __device__ __forceinline__ void gemm128(
    const bf16_t* __restrict__ A, const bf16_t* __restrict__ B,
    bf16_t* As, bf16_t* Bs, f32x4 (&acc)[4][4])
{
  const int t    = threadIdx.x;
  const int w    = t >> 6;
  const int lane = t & 63;
  const int col  = lane & 15;
  const int quad = lane >> 4;
  const int wm   = w >> 1;
  const int wn   = w & 1;

  const int sr = t >> 2;
  const int sc = (t & 3) ^ (sr & 3);          // swizzled source chunk
  const bf16_t* ga = A + (size_t)sr * DMODEL + sc * 8;
  const bf16_t* gb = B + (size_t)sr * DMODEL + sc * 8;
  const int loff = w * 512;                   // wave's stage offset (elems)
  const int swz  = (quad ^ (col & 3)) * 8;    // read-side XOR

  // prologue: stage K-tile 0 into buf 0
  load_lds16(ga,                       As + loff);
  load_lds16(ga + (size_t)64 * DMODEL, As + 2048 + loff);
  load_lds16(gb,                       Bs + loff);
  load_lds16(gb + (size_t)64 * DMODEL, Bs + 2048 + loff);

  for (int kk = 0; kk < DMODEL; kk += 32) {
    const int buf = (kk >> 5) & 1;
    __syncthreads();   // tile kk DMA complete; buf^1 free for prefetch

    if (kk + 32 < DMODEL) {
      bf16_t* An = As + (buf ^ 1) * 4096;
      bf16_t* Bn = Bs + (buf ^ 1) * 4096;
      load_lds16(ga + kk + 32,                       An + loff);
      load_lds16(ga + (size_t)64 * DMODEL + kk + 32, An + 2048 + loff);
      load_lds16(gb + kk + 32,                       Bn + loff);
      load_lds16(gb + (size_t)64 * DMODEL + kk + 32, Bn + 2048 + loff);
    }

    const bf16_t* Ab = As + buf * 4096;
    const bf16_t* Bb = Bs + buf * 4096;
    bf16x8 af[4], bfr[4];
    #pragma unroll
    for (int i = 0; i < 4; ++i) {
      af[i]  = *(const bf16x8*)(Ab + (wm * 64 + i * 16 + col) * 32 + swz);
      bfr[i] = *(const bf16x8*)(Bb + (wn * 64 + i * 16 + col) * 32 + swz);
    }
    #pragma unroll
    for (int mt = 0; mt < 4; ++mt)
      #pragma unroll
      for (int nt = 0; nt < 4; ++nt)
        acc[mt][nt] = mfma_bf16(af[mt], bfr[nt], acc[mt][nt]);
  }
}

// ---------------- QKV projection with fused RoPE epilogue ----------------
// RoPE pair (2i, 2i+1) lives in lanes (col, col^1) at the same quad/nt/r ->
// one shfl_xor(.,1) per value. (cs,sn) from the precomputed table: one 32B
// L2-resident f32x8 load per (mt,nt) covers the 4 consecutive s rows.
__global__ __launch_bounds__(256) void qkv_gemm_kernel(
    const bf16_t* __restrict__ xb, const bf16_t* __restrict__ Wall,
    const float* __restrict__ tbl,
    bf16_t* __restrict__ Qb, bf16_t* __restrict__ Kb, bf16_t* __restrict__ Vt)
{
  __shared__ __align__(16) bf16_t As[2 * 128 * 32];
  __shared__ __align__(16) bf16_t Bs[2 * 128 * 32];
  f32x4 acc[4][4] = {};
  const int m0 = blockIdx.x * 128;
  const int n0 = blockIdx.y * 128;
  gemm128(xb + (size_t)m0 * DMODEL, Wall + (size_t)n0 * DMODEL, As, Bs, acc);

  const int t = threadIdx.x;
  const int lane = t & 63, w = t >> 6;
  const int col = lane & 15, quad = lane >> 4;
  const int wm = w >> 1, wn = w & 1;
  const int nw0 = n0 + wn * 64;
  const int wt  = nw0 >> 10;          // 0=Q, 1=K, 2=V
  const int h   = (nw0 >> 6) & 15;
  const int mbase = m0 + wm * 64;

  if (wt < 2) {
    bf16_t* Out = (wt == 0) ? Qb : Kb;
    const int sgn = col & 1;          // odd d: +o*sn ; even d: -o*sn
    #pragma unroll
    for (int mt = 0; mt < 4; ++mt) {
      const int m = mbase + mt * 16 + quad * 4;
      const int b = m >> 11, s0 = m & (SEQ - 1);
      #pragma unroll
      for (int nt = 0; nt < 4; ++nt) {
        const int d = nt * 16 + col;
        const int i = nt * 8 + (col >> 1);
        f32x8 cssn = *(const f32x8*)(tbl + ((size_t)i * SEQ + s0) * 2);
        #pragma unroll
        for (int r = 0; r < 4; ++r) {
          const float e = acc[mt][nt][r];
          const float o = __shfl_xor(e, 1, 64);
          const float cs = cssn[2 * r], sn = cssn[2 * r + 1];
          const float v = sgn ? (o * sn + e * cs) : (e * cs - o * sn);
          Out[((size_t)(b * NHEADS + h) * SEQ + s0 + r) * DH + d] = (bf16_t)v;
        }
      }
    }
  } else {
    #pragma unroll
    for (int mt = 0; mt < 4; ++mt) {
      const int m = mbase + mt * 16 + quad * 4;
      const int b = m >> 11, s = m & (SEQ - 1);
      #pragma unroll
      for (int nt = 0; nt < 4; ++nt) {
        const int d = nt * 16 + col;
        bf16x4 v4 = { (bf16_t)acc[mt][nt][0], (bf16_t)acc[mt][nt][1],
                      (bf16_t)acc[mt][nt][2], (bf16_t)acc[mt][nt][3] };
        *(bf16x4*)(Vt + ((size_t)(b * NHEADS + h) * DH + d) * SEQ + s) = v4;
      }
    }
  }
}

// ---------------- Flash attention (v10 body == v6-equal best) ----------------
__global__ __launch_bounds__(256) void attn_kernel(
    const bf16_t* __restrict__ Qb, const bf16_t* __restrict__ Kb,
    const bf16_t* __restrict__ Vt, bf16_t* __restrict__ attn)
{
  __shared__ __align__(16) bf16_t Ks[2][4096];   // 2 planes x 2048 elems
  __shared__ __align__(16) bf16_t Vs[2][4096];
  __shared__ __align__(16) bf16_t Ps[4][1280];   // per wave: 2 planes x 640

  const int t    = threadIdx.x;
  const int wave = t >> 6;
  const int lane = t & 63;
  const int col  = lane & 15;
  const int quad = lane >> 4;
  const int bh = blockIdx.x;
  const int h  = bh & 15;
  const int b  = bh >> 4;
  const int qtA = blockIdx.y;          // 0..15
  const int qtB = 31 - qtA;            // 16..31

  const size_t hoff = (size_t)(b * NHEADS + h) * SEQ * DH;
  const bf16_t* Qh = Qb + hoff;
  const bf16_t* Kh = Kb + hoff;
  const bf16_t* Vh = Vt + hoff;                // (d,s), row stride SEQ

  // Q B-fragments for both phases, pre-scaled by 1/8 * log2(e)
  const int qrA = qtA * 64 + wave * 16 + col;
  const int qrB = qtB * 64 + wave * 16 + col;
  bf16x8 qfA0 = *(const bf16x8*)(Qh + (size_t)qrA * DH + quad * 8);
  bf16x8 qfA1 = *(const bf16x8*)(Qh + (size_t)qrA * DH + 32 + quad * 8);
  bf16x8 qfB0 = *(const bf16x8*)(Qh + (size_t)qrB * DH + quad * 8);
  bf16x8 qfB1 = *(const bf16x8*)(Qh + (size_t)qrB * DH + 32 + quad * 8);
  #pragma unroll
  for (int j = 0; j < 8; ++j) {
    qfA0[j] = (bf16_t)((float)qfA0[j] * 0.1803368801111191f);
    qfA1[j] = (bf16_t)((float)qfA1[j] * 0.1803368801111191f);
    qfB0[j] = (bf16_t)((float)qfB0[j] * 0.1803368801111191f);
    qfB1[j] = (bf16_t)((float)qfB1[j] * 0.1803368801111191f);
  }

  // staging map: thread t -> row t>>2, 16B chunk t&3; dst = base + t*16B
  const int sr = t >> 2, sc = t & 3;
  const int lbase = t * 8;                     // elems
  const bf16_t* kg0 = Kh + (size_t)sr * DH + sc * 8;
  const bf16_t* vg0 = Vh + (size_t)sr * SEQ + sc * 8;

  // prologue: stage tile 0 into buf 0
  load_lds16(kg0,      &Ks[0][lbase]);
  load_lds16(kg0 + 32, &Ks[0][2048 + lbase]);
  load_lds16(vg0,      &Vs[0][lbase]);
  load_lds16(vg0 + 32, &Vs[0][2048 + lbase]);

  f32x4 o[4] = {};
  float lsum = 0.0f;
  bf16_t* P = Ps[wave];
  const int lim = wave * 16 + col;             // tile-local causal limit
  const int pwoff = col * 40 + (quad >> 1) * 8 + (quad & 1) * 4;

  bf16x8 q0 = qfA0, q1 = qfA1;
  int qcur = qtA;                              // current phase's q-tile
  int it = 0;                                  // k-tile index within phase

  for (int g = 0; g <= 32; ++g) {
    const int buf = g & 1;
    __syncthreads();   // tile for step g DMA complete; buf^1 free

    if (g < 32) {      // prefetch next k-tile (tile 0 of phase B at g==qtA)
      const int nk = (g == qtA) ? 0 : (it + 1);
      const bf16_t* kg = kg0 + (size_t)nk * 64 * DH;
      const bf16_t* vg = vg0 + nk * 64;
      bf16_t* Kd = Ks[buf ^ 1];
      bf16_t* Vd = Vs[buf ^ 1];
      load_lds16(kg,      Kd + lbase);
      load_lds16(kg + 32, Kd + 2048 + lbase);
      load_lds16(vg,      Vd + lbase);
      load_lds16(vg + 32, Vd + 2048 + lbase);
    }

    const bool diag = (it == qcur);
    const bf16_t* Kbuf = Ks[buf];

    // QK^T plane a (keys 0..31) + softmax -> P plane 0
    #pragma unroll
    for (int kt = 0; kt < 2; ++kt) {
      bf16x8 ka = *(const bf16x8*)(Kbuf + (16 * kt + col) * 32 + quad * 8);
      bf16x8 kb = *(const bf16x8*)(Kbuf + 2048 + (16 * kt + col) * 32 + quad * 8);
      f32x4 s = {};
      __builtin_amdgcn_s_setprio(1);
      s = mfma_bf16(ka, q0, s);
      s = mfma_bf16(kb, q1, s);
      __builtin_amdgcn_s_setprio(0);
      const int kl = kt * 16 + quad * 4;
      bf16x4 p4;
      #pragma unroll
      for (int r = 0; r < 4; ++r) {
        float p = (!diag || (kl + r <= lim)) ? __builtin_amdgcn_exp2f(s[r]) : 0.0f;
        lsum += p;
        p4[r] = (bf16_t)p;
      }
      *(bf16x4*)(P + (kt & 1) * 16 + pwoff) = p4;
    }

    // plane-0 P fragment read: latency hides under plane-b QK below
    bf16x8 pf0 = *(const bf16x8*)(P + col * 40 + quad * 8);

    // QK^T plane b (keys 32..63) + softmax -> P plane 1
    #pragma unroll
    for (int kt = 2; kt < 4; ++kt) {
      bf16x8 ka = *(const bf16x8*)(Kbuf + (16 * kt + col) * 32 + quad * 8);
      bf16x8 kb = *(const bf16x8*)(Kbuf + 2048 + (16 * kt + col) * 32 + quad * 8);
      f32x4 s = {};
      __builtin_amdgcn_s_setprio(1);
      s = mfma_bf16(ka, q0, s);
      s = mfma_bf16(kb, q1, s);
      __builtin_amdgcn_s_setprio(0);
      const int kl = kt * 16 + quad * 4;
      bf16x4 p4;
      #pragma unroll
      for (int r = 0; r < 4; ++r) {
        float p = (!diag || (kl + r <= lim)) ? __builtin_amdgcn_exp2f(s[r]) : 0.0f;
        lsum += p;
        p4[r] = (bf16_t)p;
      }
      *(bf16x4*)(P + 640 + (kt & 1) * 16 + pwoff) = p4;
    }

    bf16x8 pf1 = *(const bf16x8*)(P + 640 + col * 40 + quad * 8);

    // PV: o[d][q] += V' * P
    const bf16_t* Vbuf = Vs[buf];
    #pragma unroll
    for (int dt = 0; dt < 4; ++dt) {
      bf16x8 va = *(const bf16x8*)(Vbuf + (16 * dt + col) * 32 + quad * 8);
      bf16x8 vb = *(const bf16x8*)(Vbuf + 2048 + (16 * dt + col) * 32 + quad * 8);
      __builtin_amdgcn_s_setprio(1);
      o[dt] = mfma_bf16(va, pf0, o[dt]);
      o[dt] = mfma_bf16(vb, pf1, o[dt]);
      __builtin_amdgcn_s_setprio(0);
    }

    if (diag) {
      // finalize current phase: reduce lsum across quads, normalize, store
      float ls = lsum;
      ls += __shfl_xor(ls, 16, 64);
      ls += __shfl_xor(ls, 32, 64);
      const float inv = 1.0f / ls;
      const int q = qcur * 64 + wave * 16 + col;
      const size_t orow = (size_t)(b * SEQ + q) * DMODEL + h * DH;
      #pragma unroll
      for (int dt = 0; dt < 4; ++dt) {
        bf16x4 v4 = { (bf16_t)(o[dt][0] * inv), (bf16_t)(o[dt][1] * inv),
                      (bf16_t)(o[dt][2] * inv), (bf16_t)(o[dt][3] * inv) };
        *(bf16x4*)(attn + orow + dt * 16 + quad * 4) = v4;
      }
      // switch to phase B
      #pragma unroll
      for (int dt = 0; dt < 4; ++dt) o[dt] = f32x4{};
      lsum = 0.0f;
      q0 = qfB0; q1 = qfB1;
      qcur = qtB;
      it = 0;
    } else {
      ++it;
    }
  }
}

// ---------------- Output projection (-> f32 d_out) ----------------
__global__ __launch_bounds__(256) void out_gemm_kernel(
    const bf16_t* __restrict__ Ab, const bf16_t* __restrict__ Wob,
    float* __restrict__ out)
{
  __shared__ __align__(16) bf16_t As[2 * 128 * 32];
  __shared__ __align__(16) bf16_t Bs[2 * 128 * 32];
  f32x4 acc[4][4] = {};
  const int m0 = blockIdx.x * 128;
  const int n0 = blockIdx.y * 128;
  gemm128(Ab + (size_t)m0 * DMODEL, Wob + (size_t)n0 * DMODEL, As, Bs, acc);

  const int t = threadIdx.x;
  const int lane = t & 63, w = t >> 6;
  const int col = lane & 15, quad = lane >> 4;
  const int wm = w >> 1, wn = w & 1;
  const int mbase = m0 + wm * 64;
  const int nbase = n0 + wn * 64;

  #pragma unroll
  for (int mt = 0; mt < 4; ++mt)
    #pragma unroll
    for (int nt = 0; nt < 4; ++nt)
      #pragma unroll
      for (int r = 0; r < 4; ++r)
        out[(size_t)(mbase + mt * 16 + quad * 4 + r) * DMODEL + nbase + nt * 16 + col] =
            acc[mt][nt][r];
}

extern "C" void kernel_launch(void* const* d_in, const int* in_sizes, int n_in,
                              void* d_out, int out_size, void* d_ws, size_t ws_size,
                              hipStream_t stream)
{
  (void)in_sizes; (void)n_in; (void)out_size; (void)ws_size;
  const float* x  = (const float*)d_in[0];
  const float* Wq = (const float*)d_in[1];
  const float* Wk = (const float*)d_in[2];
  const float* Wv = (const float*)d_in[3];
  const float* Wo = (const float*)d_in[4];
  const int* tpos = (const int*)d_in[5];
  float* out = (float*)d_out;

  const size_t M1 = (size_t)1024 * 1024;
  bf16_t* xb    = (bf16_t*)d_ws;                  // 4M elems
  bf16_t* Wall  = xb + 4 * M1;                    // Wq|Wk|Wv (3M)
  bf16_t* Wob   = xb + 7 * M1;                    // 1M
  bf16_t* Qb    = xb + 8 * M1;                    // 4M  (b,h,s,d)
  bf16_t* Kb    = Qb + 4 * M1;                    // 4M  (b,h,s,d)
  bf16_t* Vt    = Kb + 4 * M1;                    // 4M  (b,h,d,s)
  bf16_t* attnb = Vt + 4 * M1;                    // 4M  (b*s, h*d)
  float*  tbl   = (float*)(attnb + 4 * M1);       // 64K float2 (512KB)

  convert_kernel<<<dim3(4352, 1, 1), dim3(256, 1, 1), 0, stream>>>(
      x, Wq, Wk, Wv, Wo, tpos, xb, tbl);
  qkv_gemm_kernel<<<dim3(32, 24, 1), dim3(256, 1, 1), 0, stream>>>(
      xb, Wall, tbl, Qb, Kb, Vt);
  attn_kernel<<<dim3(32, 16, 1), dim3(256, 1, 1), 0, stream>>>(
      Qb, Kb, Vt, attnb);
  out_gemm_kernel<<<dim3(32, 8, 1), dim3(256, 1, 1), 0, stream>>>(
      attnb, Wob, out);
}

// Round 7
// 198.336 us; speedup vs baseline: 1.0149x; 1.0149x over previous
//
#include <hip/hip_runtime.h>
#include <math.h>

typedef __bf16 bf16_t;
typedef __bf16 bf16x4 __attribute__((ext_vector_type(4)));
typedef __bf16 bf16x8 __attribute__((ext_vector_type(8)));
typedef float  f32x4  __attribute__((ext_vector_type(4)));
typedef float  f32x8  __attribute__((ext_vector_type(8)));

#define NHEADS 16
#define DH 64
#define SEQ 2048
#define DMODEL 1024

static __device__ __forceinline__ f32x4 mfma_bf16(bf16x8 a, bf16x8 b, f32x4 c) {
  return __builtin_amdgcn_mfma_f32_16x16x32_bf16(a, b, c, 0, 0, 0);
}

// async global->LDS, 16B per lane; LDS dest = wave-uniform base + lane*16
static __device__ __forceinline__ void load_lds16(const bf16_t* g, bf16_t* l) {
  __builtin_amdgcn_global_load_lds(
      (const __attribute__((address_space(1))) void*)g,
      (__attribute__((address_space(3))) void*)l, 16, 0, 0);
}

// ---------------- f32 -> bf16 pre-convert + RoPE table ----------------
// flat dst layout: x(4M) | Wq(1M) | Wk(1M) | Wv(1M) | Wo(1M) elems
// blocks >= 4096 fill tbl[i][s] = (cos, sin)(tpos[s] * theta^(-i/32)),
// i in 0..31, s in 0..2047 -> 512KB, L2-resident for the qkv epilogue.
__global__ __launch_bounds__(256) void convert_kernel(
    const float* __restrict__ x, const float* __restrict__ Wq,
    const float* __restrict__ Wk, const float* __restrict__ Wv,
    const float* __restrict__ Wo, const int* __restrict__ tpos,
    bf16_t* __restrict__ dst, float* __restrict__ tbl)
{
  if (blockIdx.x >= 4096) {
    const int idx2 = (blockIdx.x - 4096) * 256 + threadIdx.x;  // 0..65535
    const int i = idx2 >> 11;          // 0..31
    const int s = idx2 & (SEQ - 1);    // 0..2047
    const float pos  = (float)tpos[s];
    const float freq = expf((float)i * -0.28782313662425573f);
    const float ang  = pos * freq;
    tbl[(size_t)idx2 * 2]     = cosf(ang);
    tbl[(size_t)idx2 * 2 + 1] = sinf(ang);
    return;
  }
  const size_t idx = ((size_t)blockIdx.x * 256 + threadIdx.x) * 8;
  const size_t XN = (size_t)4096 * DMODEL;
  const float* src;
  size_t off;
  if (idx < XN) { src = x; off = idx; }
  else {
    size_t r = idx - XN;
    int q = (int)(r >> 20);
    off = r & ((size_t)(1u << 20) - 1);
    src = (q == 0) ? Wq : (q == 1) ? Wk : (q == 2) ? Wv : Wo;
  }
  f32x8 v = *(const f32x8*)(src + off);
  bf16x8 o;
  #pragma unroll
  for (int j = 0; j < 8; ++j) o[j] = (bf16_t)v[j];
  *(bf16x8*)(dst + idx) = o;
}

// ---------------- 128x64 GEMM core, 2-wave blocks, single-buffered ----------
// v13: smaller blocks for TLP. v11's 128x128/4-wave blocks gave only 3/CU
// (qkv) and 1/CU (out) residency; the per-K-step vmcnt drain at the barrier
// (structural, m97) was uncovered -> 510 TF. 128x64 / 128-thread blocks:
// qkv 6 blocks/CU, out 2/CU, 2-wave barriers. Same v11 schedule (stage ->
// barrier/drain -> ds_read+MFMA -> barrier), same XOR swizzle; dbuf reverted
// (measured -7us: __syncthreads drains vmcnt(0) anyway + LDS port contention).
// LDS: A 128x32 (8KB) + B 64x32 (4KB). Wave w owns m-rows [64w,64w+64).
static __device__ __forceinline__ void gemm12864(
    const bf16_t* __restrict__ A, const bf16_t* __restrict__ B,
    bf16_t* As, bf16_t* Bs, f32x4 (&acc)[4][4])
{
  const int t    = threadIdx.x;               // 0..127
  const int w    = t >> 6;                    // 0..1
  const int lane = t & 63;
  const int col  = lane & 15;
  const int quad = lane >> 4;

  const int sr = t >> 2;                      // 0..31
  const int sc = (t & 3) ^ (sr & 3);          // swizzled source chunk
  const bf16_t* ga = A + (size_t)sr * DMODEL + sc * 8;
  const bf16_t* gb = B + (size_t)sr * DMODEL + sc * 8;
  bf16_t* la = As + t * 8;
  bf16_t* lb = Bs + t * 8;
  const int swz = (quad ^ (col & 3)) * 8;     // read-side XOR

  for (int kk = 0; kk < DMODEL; kk += 32) {
    load_lds16(ga + kk,                       la);          // A rows  0..31
    load_lds16(ga + (size_t)32 * DMODEL + kk, la + 1024);   // A rows 32..63
    load_lds16(ga + (size_t)64 * DMODEL + kk, la + 2048);   // A rows 64..95
    load_lds16(ga + (size_t)96 * DMODEL + kk, la + 3072);   // A rows 96..127
    load_lds16(gb + kk,                       lb);          // B rows  0..31
    load_lds16(gb + (size_t)32 * DMODEL + kk, lb + 1024);   // B rows 32..63
    __syncthreads();

    bf16x8 af[4], bfr[4];
    #pragma unroll
    for (int i = 0; i < 4; ++i) {
      af[i]  = *(const bf16x8*)(As + (w * 64 + i * 16 + col) * 32 + swz);
      bfr[i] = *(const bf16x8*)(Bs + (i * 16 + col) * 32 + swz);
    }
    #pragma unroll
    for (int mt = 0; mt < 4; ++mt)
      #pragma unroll
      for (int nt = 0; nt < 4; ++nt)
        acc[mt][nt] = mfma_bf16(af[mt], bfr[nt], acc[mt][nt]);
    __syncthreads();
  }
}

// ---------------- QKV projection with fused RoPE epilogue ----------------
// Each y-block covers one 64-col span = exactly one (type, head):
// wt = y>>4 (0=Q,1=K,2=V), h = y&15. RoPE pair (2i,2i+1) in lanes (col,col^1)
// same quad/nt/r -> one shfl_xor per value; (cs,sn) from the L2-resident tbl.
__global__ __launch_bounds__(128) void qkv_gemm_kernel(
    const bf16_t* __restrict__ xb, const bf16_t* __restrict__ Wall,
    const float* __restrict__ tbl,
    bf16_t* __restrict__ Qb, bf16_t* __restrict__ Kb, bf16_t* __restrict__ Vt)
{
  __shared__ __align__(16) bf16_t As[128 * 32];
  __shared__ __align__(16) bf16_t Bs[64 * 32];
  f32x4 acc[4][4] = {};
  const int m0 = blockIdx.x * 128;
  const int n0 = blockIdx.y * 64;
  gemm12864(xb + (size_t)m0 * DMODEL, Wall + (size_t)n0 * DMODEL, As, Bs, acc);

  const int t = threadIdx.x;
  const int lane = t & 63, w = t >> 6;
  const int col = lane & 15, quad = lane >> 4;
  const int wt  = n0 >> 10;           // 0=Q, 1=K, 2=V
  const int h   = (n0 >> 6) & 15;
  const int mbase = m0 + w * 64;

  if (wt < 2) {
    bf16_t* Out = (wt == 0) ? Qb : Kb;
    const int sgn = col & 1;          // odd d: +o*sn ; even d: -o*sn
    #pragma unroll
    for (int mt = 0; mt < 4; ++mt) {
      const int m = mbase + mt * 16 + quad * 4;
      const int b = m >> 11, s0 = m & (SEQ - 1);
      #pragma unroll
      for (int nt = 0; nt < 4; ++nt) {
        const int d = nt * 16 + col;
        const int i = nt * 8 + (col >> 1);
        f32x8 cssn = *(const f32x8*)(tbl + ((size_t)i * SEQ + s0) * 2);
        #pragma unroll
        for (int r = 0; r < 4; ++r) {
          const float e = acc[mt][nt][r];
          const float o = __shfl_xor(e, 1, 64);
          const float cs = cssn[2 * r], sn = cssn[2 * r + 1];
          const float v = sgn ? (o * sn + e * cs) : (e * cs - o * sn);
          Out[((size_t)(b * NHEADS + h) * SEQ + s0 + r) * DH + d] = (bf16_t)v;
        }
      }
    }
  } else {
    #pragma unroll
    for (int mt = 0; mt < 4; ++mt) {
      const int m = mbase + mt * 16 + quad * 4;
      const int b = m >> 11, s = m & (SEQ - 1);
      #pragma unroll
      for (int nt = 0; nt < 4; ++nt) {
        const int d = nt * 16 + col;
        bf16x4 v4 = { (bf16_t)acc[mt][nt][0], (bf16_t)acc[mt][nt][1],
                      (bf16_t)acc[mt][nt][2], (bf16_t)acc[mt][nt][3] };
        *(bf16x4*)(Vt + ((size_t)(b * NHEADS + h) * DH + d) * SEQ + s) = v4;
      }
    }
  }
}

// ---------------- Flash attention (v10 body == v6-equal best) ----------------
__global__ __launch_bounds__(256) void attn_kernel(
    const bf16_t* __restrict__ Qb, const bf16_t* __restrict__ Kb,
    const bf16_t* __restrict__ Vt, bf16_t* __restrict__ attn)
{
  __shared__ __align__(16) bf16_t Ks[2][4096];   // 2 planes x 2048 elems
  __shared__ __align__(16) bf16_t Vs[2][4096];
  __shared__ __align__(16) bf16_t Ps[4][1280];   // per wave: 2 planes x 640

  const int t    = threadIdx.x;
  const int wave = t >> 6;
  const int lane = t & 63;
  const int col  = lane & 15;
  const int quad = lane >> 4;
  const int bh = blockIdx.x;
  const int h  = bh & 15;
  const int b  = bh >> 4;
  const int qtA = blockIdx.y;          // 0..15
  const int qtB = 31 - qtA;            // 16..31

  const size_t hoff = (size_t)(b * NHEADS + h) * SEQ * DH;
  const bf16_t* Qh = Qb + hoff;
  const bf16_t* Kh = Kb + hoff;
  const bf16_t* Vh = Vt + hoff;                // (d,s), row stride SEQ

  // Q B-fragments for both phases, pre-scaled by 1/8 * log2(e)
  const int qrA = qtA * 64 + wave * 16 + col;
  const int qrB = qtB * 64 + wave * 16 + col;
  bf16x8 qfA0 = *(const bf16x8*)(Qh + (size_t)qrA * DH + quad * 8);
  bf16x8 qfA1 = *(const bf16x8*)(Qh + (size_t)qrA * DH + 32 + quad * 8);
  bf16x8 qfB0 = *(const bf16x8*)(Qh + (size_t)qrB * DH + quad * 8);
  bf16x8 qfB1 = *(const bf16x8*)(Qh + (size_t)qrB * DH + 32 + quad * 8);
  #pragma unroll
  for (int j = 0; j < 8; ++j) {
    qfA0[j] = (bf16_t)((float)qfA0[j] * 0.1803368801111191f);
    qfA1[j] = (bf16_t)((float)qfA1[j] * 0.1803368801111191f);
    qfB0[j] = (bf16_t)((float)qfB0[j] * 0.1803368801111191f);
    qfB1[j] = (bf16_t)((float)qfB1[j] * 0.1803368801111191f);
  }

  // staging map: thread t -> row t>>2, 16B chunk t&3; dst = base + t*16B
  const int sr = t >> 2, sc = t & 3;
  const int lbase = t * 8;                     // elems
  const bf16_t* kg0 = Kh + (size_t)sr * DH + sc * 8;
  const bf16_t* vg0 = Vh + (size_t)sr * SEQ + sc * 8;

  // prologue: stage tile 0 into buf 0
  load_lds16(kg0,      &Ks[0][lbase]);
  load_lds16(kg0 + 32, &Ks[0][2048 + lbase]);
  load_lds16(vg0,      &Vs[0][lbase]);
  load_lds16(vg0 + 32, &Vs[0][2048 + lbase]);

  f32x4 o[4] = {};
  float lsum = 0.0f;
  bf16_t* P = Ps[wave];
  const int lim = wave * 16 + col;             // tile-local causal limit
  const int pwoff = col * 40 + (quad >> 1) * 8 + (quad & 1) * 4;

  bf16x8 q0 = qfA0, q1 = qfA1;
  int qcur = qtA;                              // current phase's q-tile
  int it = 0;                                  // k-tile index within phase

  for (int g = 0; g <= 32; ++g) {
    const int buf = g & 1;
    __syncthreads();   // tile for step g DMA complete; buf^1 free

    if (g < 32) {      // prefetch next k-tile (tile 0 of phase B at g==qtA)
      const int nk = (g == qtA) ? 0 : (it + 1);
      const bf16_t* kg = kg0 + (size_t)nk * 64 * DH;
      const bf16_t* vg = vg0 + nk * 64;
      bf16_t* Kd = Ks[buf ^ 1];
      bf16_t* Vd = Vs[buf ^ 1];
      load_lds16(kg,      Kd + lbase);
      load_lds16(kg + 32, Kd + 2048 + lbase);
      load_lds16(vg,      Vd + lbase);
      load_lds16(vg + 32, Vd + 2048 + lbase);
    }

    const bool diag = (it == qcur);
    const bf16_t* Kbuf = Ks[buf];

    // QK^T plane a (keys 0..31) + softmax -> P plane 0
    #pragma unroll
    for (int kt = 0; kt < 2; ++kt) {
      bf16x8 ka = *(const bf16x8*)(Kbuf + (16 * kt + col) * 32 + quad * 8);
      bf16x8 kb = *(const bf16x8*)(Kbuf + 2048 + (16 * kt + col) * 32 + quad * 8);
      f32x4 s = {};
      __builtin_amdgcn_s_setprio(1);
      s = mfma_bf16(ka, q0, s);
      s = mfma_bf16(kb, q1, s);
      __builtin_amdgcn_s_setprio(0);
      const int kl = kt * 16 + quad * 4;
      bf16x4 p4;
      #pragma unroll
      for (int r = 0; r < 4; ++r) {
        float p = (!diag || (kl + r <= lim)) ? __builtin_amdgcn_exp2f(s[r]) : 0.0f;
        lsum += p;
        p4[r] = (bf16_t)p;
      }
      *(bf16x4*)(P + (kt & 1) * 16 + pwoff) = p4;
    }

    // plane-0 P fragment read: latency hides under plane-b QK below
    bf16x8 pf0 = *(const bf16x8*)(P + col * 40 + quad * 8);

    // QK^T plane b (keys 32..63) + softmax -> P plane 1
    #pragma unroll
    for (int kt = 2; kt < 4; ++kt) {
      bf16x8 ka = *(const bf16x8*)(Kbuf + (16 * kt + col) * 32 + quad * 8);
      bf16x8 kb = *(const bf16x8*)(Kbuf + 2048 + (16 * kt + col) * 32 + quad * 8);
      f32x4 s = {};
      __builtin_amdgcn_s_setprio(1);
      s = mfma_bf16(ka, q0, s);
      s = mfma_bf16(kb, q1, s);
      __builtin_amdgcn_s_setprio(0);
      const int kl = kt * 16 + quad * 4;
      bf16x4 p4;
      #pragma unroll
      for (int r = 0; r < 4; ++r) {
        float p = (!diag || (kl + r <= lim)) ? __builtin_amdgcn_exp2f(s[r]) : 0.0f;
        lsum += p;
        p4[r] = (bf16_t)p;
      }
      *(bf16x4*)(P + 640 + (kt & 1) * 16 + pwoff) = p4;
    }

    bf16x8 pf1 = *(const bf16x8*)(P + 640 + col * 40 + quad * 8);

    // PV: o[d][q] += V' * P
    const bf16_t* Vbuf = Vs[buf];
    #pragma unroll
    for (int dt = 0; dt < 4; ++dt) {
      bf16x8 va = *(const bf16x8*)(Vbuf + (16 * dt + col) * 32 + quad * 8);
      bf16x8 vb = *(const bf16x8*)(Vbuf + 2048 + (16 * dt + col) * 32 + quad * 8);
      __builtin_amdgcn_s_setprio(1);
      o[dt] = mfma_bf16(va, pf0, o[dt]);
      o[dt] = mfma_bf16(vb, pf1, o[dt]);
      __builtin_amdgcn_s_setprio(0);
    }

    if (diag) {
      // finalize current phase: reduce lsum across quads, normalize, store
      float ls = lsum;
      ls += __shfl_xor(ls, 16, 64);
      ls += __shfl_xor(ls, 32, 64);
      const float inv = 1.0f / ls;
      const int q = qcur * 64 + wave * 16 + col;
      const size_t orow = (size_t)(b * SEQ + q) * DMODEL + h * DH;
      #pragma unroll
      for (int dt = 0; dt < 4; ++dt) {
        bf16x4 v4 = { (bf16_t)(o[dt][0] * inv), (bf16_t)(o[dt][1] * inv),
                      (bf16_t)(o[dt][2] * inv), (bf16_t)(o[dt][3] * inv) };
        *(bf16x4*)(attn + orow + dt * 16 + quad * 4) = v4;
      }
      // switch to phase B
      #pragma unroll
      for (int dt = 0; dt < 4; ++dt) o[dt] = f32x4{};
      lsum = 0.0f;
      q0 = qfB0; q1 = qfB1;
      qcur = qtB;
      it = 0;
    } else {
      ++it;
    }
  }
}

// ---------------- Output projection (-> f32 d_out) ----------------
__global__ __launch_bounds__(128) void out_gemm_kernel(
    const bf16_t* __restrict__ Ab, const bf16_t* __restrict__ Wob,
    float* __restrict__ out)
{
  __shared__ __align__(16) bf16_t As[128 * 32];
  __shared__ __align__(16) bf16_t Bs[64 * 32];
  f32x4 acc[4][4] = {};
  const int m0 = blockIdx.x * 128;
  const int n0 = blockIdx.y * 64;
  gemm12864(Ab + (size_t)m0 * DMODEL, Wob + (size_t)n0 * DMODEL, As, Bs, acc);

  const int t = threadIdx.x;
  const int lane = t & 63, w = t >> 6;
  const int col = lane & 15, quad = lane >> 4;
  const int mbase = m0 + w * 64;

  #pragma unroll
  for (int mt = 0; mt < 4; ++mt)
    #pragma unroll
    for (int nt = 0; nt < 4; ++nt)
      #pragma unroll
      for (int r = 0; r < 4; ++r)
        out[(size_t)(mbase + mt * 16 + quad * 4 + r) * DMODEL + n0 + nt * 16 + col] =
            acc[mt][nt][r];
}

extern "C" void kernel_launch(void* const* d_in, const int* in_sizes, int n_in,
                              void* d_out, int out_size, void* d_ws, size_t ws_size,
                              hipStream_t stream)
{
  (void)in_sizes; (void)n_in; (void)out_size; (void)ws_size;
  const float* x  = (const float*)d_in[0];
  const float* Wq = (const float*)d_in[1];
  const float* Wk = (const float*)d_in[2];
  const float* Wv = (const float*)d_in[3];
  const float* Wo = (const float*)d_in[4];
  const int* tpos = (const int*)d_in[5];
  float* out = (float*)d_out;

  const size_t M1 = (size_t)1024 * 1024;
  bf16_t* xb    = (bf16_t*)d_ws;                  // 4M elems
  bf16_t* Wall  = xb + 4 * M1;                    // Wq|Wk|Wv (3M)
  bf16_t* Wob   = xb + 7 * M1;                    // 1M
  bf16_t* Qb    = xb + 8 * M1;                    // 4M  (b,h,s,d)
  bf16_t* Kb    = Qb + 4 * M1;                    // 4M  (b,h,s,d)
  bf16_t* Vt    = Kb + 4 * M1;                    // 4M  (b,h,d,s)
  bf16_t* attnb = Vt + 4 * M1;                    // 4M  (b*s, h*d)
  float*  tbl   = (float*)(attnb + 4 * M1);       // 64K float2 (512KB)

  convert_kernel<<<dim3(4352, 1, 1), dim3(256, 1, 1), 0, stream>>>(
      x, Wq, Wk, Wv, Wo, tpos, xb, tbl);
  qkv_gemm_kernel<<<dim3(32, 48, 1), dim3(128, 1, 1), 0, stream>>>(
      xb, Wall, tbl, Qb, Kb, Vt);
  attn_kernel<<<dim3(32, 16, 1), dim3(256, 1, 1), 0, stream>>>(
      Qb, Kb, Vt, attnb);
  out_gemm_kernel<<<dim3(32, 16, 1), dim3(128, 1, 1), 0, stream>>>(
      attnb, Wob, out);
}

// Round 8
// 191.670 us; speedup vs baseline: 1.0502x; 1.0348x over previous
//
#include <hip/hip_runtime.h>
#include <math.h>

typedef __bf16 bf16_t;
typedef __bf16 bf16x4 __attribute__((ext_vector_type(4)));
typedef __bf16 bf16x8 __attribute__((ext_vector_type(8)));
typedef float  f32x4  __attribute__((ext_vector_type(4)));
typedef float  f32x8  __attribute__((ext_vector_type(8)));

#define NHEADS 16
#define DH 64
#define SEQ 2048
#define DMODEL 1024

static __device__ __forceinline__ f32x4 mfma_bf16(bf16x8 a, bf16x8 b, f32x4 c) {
  return __builtin_amdgcn_mfma_f32_16x16x32_bf16(a, b, c, 0, 0, 0);
}

// async global->LDS, 16B per lane; LDS dest = wave-uniform base + lane*16
static __device__ __forceinline__ void load_lds16(const bf16_t* g, bf16_t* l) {
  __builtin_amdgcn_global_load_lds(
      (const __attribute__((address_space(1))) void*)g,
      (__attribute__((address_space(3))) void*)l, 16, 0, 0);
}

// ---------------- f32 -> bf16 pre-convert ----------------
// flat dst layout: x(4M) | Wq(1M) | Wk(1M) | Wv(1M) | Wo(1M) elems
__global__ __launch_bounds__(256) void convert_kernel(
    const float* __restrict__ x, const float* __restrict__ Wq,
    const float* __restrict__ Wk, const float* __restrict__ Wv,
    const float* __restrict__ Wo, bf16_t* __restrict__ dst)
{
  const size_t idx = ((size_t)blockIdx.x * 256 + threadIdx.x) * 8;
  const size_t XN = (size_t)4096 * DMODEL;
  const float* src;
  size_t off;
  if (idx < XN) { src = x; off = idx; }
  else {
    size_t r = idx - XN;
    int q = (int)(r >> 20);
    off = r & ((size_t)(1u << 20) - 1);
    src = (q == 0) ? Wq : (q == 1) ? Wk : (q == 2) ? Wv : Wo;
  }
  f32x8 v = *(const f32x8*)(src + off);
  bf16x8 o;
  #pragma unroll
  for (int j = 0; j < 8; ++j) o[j] = (bf16_t)v[j];
  *(bf16x8*)(dst + idx) = o;
}

// ---------------- shared 128x128 GEMM core (m97 structure) ----------------
static __device__ __forceinline__ void gemm128(
    const bf16_t* __restrict__ A, const bf16_t* __restrict__ B,
    bf16_t* As, bf16_t* Bs, f32x4 (&acc)[4][4])
{
  const int t    = threadIdx.x;
  const int w    = t >> 6;
  const int lane = t & 63;
  const int col  = lane & 15;
  const int quad = lane >> 4;
  const int wm   = w >> 1;
  const int wn   = w & 1;

  const bf16_t* ga = A + (size_t)(t >> 2) * DMODEL + (t & 3) * 8;
  const bf16_t* gb = B + (size_t)(t >> 2) * DMODEL + (t & 3) * 8;
  bf16_t* la = As + w * 512;
  bf16_t* lb = Bs + w * 512;

  for (int kk = 0; kk < DMODEL; kk += 32) {
    load_lds16(ga + kk, la);
    load_lds16(ga + (size_t)64 * DMODEL + kk, la + 2048);
    load_lds16(gb + kk, lb);
    load_lds16(gb + (size_t)64 * DMODEL + kk, lb + 2048);
    __syncthreads();

    bf16x8 af[4], bfr[4];
    #pragma unroll
    for (int i = 0; i < 4; ++i) {
      af[i]  = *(const bf16x8*)(As + (wm * 64 + i * 16 + col) * 32 + quad * 8);
      bfr[i] = *(const bf16x8*)(Bs + (wn * 64 + i * 16 + col) * 32 + quad * 8);
    }
    #pragma unroll
    for (int mt = 0; mt < 4; ++mt)
      #pragma unroll
      for (int nt = 0; nt < 4; ++nt)
        acc[mt][nt] = mfma_bf16(af[mt], bfr[nt], acc[mt][nt]);
    __syncthreads();
  }
}

// ---------------- QKV projection ----------------
__global__ __launch_bounds__(256) void qkv_gemm_kernel(
    const bf16_t* __restrict__ xb, const bf16_t* __restrict__ Wall,
    bf16_t* __restrict__ Qb, bf16_t* __restrict__ Kb, bf16_t* __restrict__ Vt)
{
  __shared__ __align__(16) bf16_t As[128 * 32];
  __shared__ __align__(16) bf16_t Bs[128 * 32];
  f32x4 acc[4][4] = {};
  const int m0 = blockIdx.x * 128;
  const int n0 = blockIdx.y * 128;
  gemm128(xb + (size_t)m0 * DMODEL, Wall + (size_t)n0 * DMODEL, As, Bs, acc);

  const int t = threadIdx.x;
  const int lane = t & 63, w = t >> 6;
  const int col = lane & 15, quad = lane >> 4;
  const int wm = w >> 1, wn = w & 1;
  const int nw0 = n0 + wn * 64;
  const int wt  = nw0 >> 10;          // 0=Q, 1=K, 2=V
  const int h   = (nw0 >> 6) & 15;
  const int mbase = m0 + wm * 64;

  if (wt < 2) {
    bf16_t* Out = (wt == 0) ? Qb : Kb;
    #pragma unroll
    for (int mt = 0; mt < 4; ++mt) {
      #pragma unroll
      for (int nt = 0; nt < 4; ++nt) {
        const int d = nt * 16 + col;
        #pragma unroll
        for (int r = 0; r < 4; ++r) {
          const int m = mbase + mt * 16 + quad * 4 + r;
          const int b = m >> 11, s = m & (SEQ - 1);
          Out[((size_t)(b * NHEADS + h) * SEQ + s) * DH + d] = (bf16_t)acc[mt][nt][r];
        }
      }
    }
  } else {
    #pragma unroll
    for (int mt = 0; mt < 4; ++mt) {
      const int m = mbase + mt * 16 + quad * 4;
      const int b = m >> 11, s = m & (SEQ - 1);
      #pragma unroll
      for (int nt = 0; nt < 4; ++nt) {
        const int d = nt * 16 + col;
        bf16x4 v4 = { (bf16_t)acc[mt][nt][0], (bf16_t)acc[mt][nt][1],
                      (bf16_t)acc[mt][nt][2], (bf16_t)acc[mt][nt][3] };
        *(bf16x4*)(Vt + ((size_t)(b * NHEADS + h) * DH + d) * SEQ + s) = v4;
      }
    }
  }
}

// ---------------- RoPE (in-place on Q and K) ----------------
__global__ __launch_bounds__(256) void rope_kernel(
    bf16_t* __restrict__ Qb, bf16_t* __restrict__ Kb, const int* __restrict__ tpos)
{
  const int idx = blockIdx.x * 256 + threadIdx.x;
  const int i  = idx & 31;
  const int s  = (idx >> 5) & (SEQ - 1);
  const int bh = idx >> 16;

  const float pos  = (float)tpos[s];
  const float freq = expf((float)i * -0.28782313662425573f);
  const float ang  = pos * freq;
  const float cs = cosf(ang), sn = sinf(ang);

  const size_t base = ((size_t)bh * SEQ + s) * DH + 2 * i;
  {
    float e = (float)Qb[base], o = (float)Qb[base + 1];
    Qb[base]     = (bf16_t)(e * cs - o * sn);
    Qb[base + 1] = (bf16_t)(e * sn + o * cs);
  }
  {
    float e = (float)Kb[base], o = (float)Kb[base + 1];
    Kb[base]     = (bf16_t)(e * cs - o * sn);
    Kb[base + 1] = (bf16_t)(e * sn + o * cs);
  }
}

// ---------------- Flash attention v14 ----------------
// v6 body with the P LDS round-trip ELIMINATED. Key identity: the QK MFMA's
// A-operand rows are addressed by `col`, outputs land at rows quad*4+r. By
// permuting which K-rows each lane loads (row = 8*(col>>2)+(col&3) + 4i
// [+32 for plane b]), MFMA #i's output at lane(col,quad) IS P[key=8*quad +
// 4*(i&1)+r][q=col] -- exactly PV's B-fragment element (i&1)*4+r (the old P
// buffer stored key k at row offset k, read back as elements quad*8+j).
// So pf0/pf1 are built in-register from the masked exp2 results: removes
// 4 ds_write_b64 + 2 ds_read_b128 + 2 lgkm waits per tile-step and the Ps
// buffer (LDS 43008 -> 32768). K-read bank pattern unchanged (row parity).
__global__ __launch_bounds__(256) void attn_kernel(
    const bf16_t* __restrict__ Qb, const bf16_t* __restrict__ Kb,
    const bf16_t* __restrict__ Vt, bf16_t* __restrict__ attn)
{
  __shared__ __align__(16) bf16_t Ks[2][4096];   // 2 d-halves x (64 keys x 32)
  __shared__ __align__(16) bf16_t Vs[2][4096];   // 2 key-halves x (64 d x 32)

  const int t    = threadIdx.x;
  const int wave = t >> 6;
  const int lane = t & 63;
  const int col  = lane & 15;
  const int quad = lane >> 4;
  const int bh = blockIdx.x;
  const int h  = bh & 15;
  const int b  = bh >> 4;
  const int qtA = blockIdx.y;          // 0..15
  const int qtB = 31 - qtA;            // 16..31

  const size_t hoff = (size_t)(b * NHEADS + h) * SEQ * DH;
  const bf16_t* Qh = Qb + hoff;
  const bf16_t* Kh = Kb + hoff;
  const bf16_t* Vh = Vt + hoff;                // (d,s), row stride SEQ

  // Q B-fragments for both phases, pre-scaled by 1/8 * log2(e)
  const int qrA = qtA * 64 + wave * 16 + col;
  const int qrB = qtB * 64 + wave * 16 + col;
  bf16x8 qfA0 = *(const bf16x8*)(Qh + (size_t)qrA * DH + quad * 8);
  bf16x8 qfA1 = *(const bf16x8*)(Qh + (size_t)qrA * DH + 32 + quad * 8);
  bf16x8 qfB0 = *(const bf16x8*)(Qh + (size_t)qrB * DH + quad * 8);
  bf16x8 qfB1 = *(const bf16x8*)(Qh + (size_t)qrB * DH + 32 + quad * 8);
  #pragma unroll
  for (int j = 0; j < 8; ++j) {
    qfA0[j] = (bf16_t)((float)qfA0[j] * 0.1803368801111191f);
    qfA1[j] = (bf16_t)((float)qfA1[j] * 0.1803368801111191f);
    qfB0[j] = (bf16_t)((float)qfB0[j] * 0.1803368801111191f);
    qfB1[j] = (bf16_t)((float)qfB1[j] * 0.1803368801111191f);
  }

  // staging map: thread t -> row t>>2, 16B chunk t&3; dst = base + t*16B
  const int sr = t >> 2, sc = t & 3;
  const int lbase = t * 8;                     // elems
  const bf16_t* kg0 = Kh + (size_t)sr * DH + sc * 8;
  const bf16_t* vg0 = Vh + (size_t)sr * SEQ + sc * 8;

  // prologue: stage tile 0 into buf 0
  load_lds16(kg0,      &Ks[0][lbase]);
  load_lds16(kg0 + 32, &Ks[0][2048 + lbase]);
  load_lds16(vg0,      &Vs[0][lbase]);
  load_lds16(vg0 + 32, &Vs[0][2048 + lbase]);

  f32x4 o[4] = {};
  float lsum = 0.0f;
  const int lim = wave * 16 + col;             // tile-local causal limit
  const int fr  = 8 * (col >> 2) + (col & 3);  // permuted K-row base

  bf16x8 q0 = qfA0, q1 = qfA1;
  int qcur = qtA;                              // current phase's q-tile
  int it = 0;                                  // k-tile index within phase

  for (int g = 0; g <= 32; ++g) {
    const int buf = g & 1;
    __syncthreads();   // tile for step g DMA complete; buf^1 free

    if (g < 32) {      // prefetch next k-tile (tile 0 of phase B at g==qtA)
      const int nk = (g == qtA) ? 0 : (it + 1);
      const bf16_t* kg = kg0 + (size_t)nk * 64 * DH;
      const bf16_t* vg = vg0 + nk * 64;
      bf16_t* Kd = Ks[buf ^ 1];
      bf16_t* Vd = Vs[buf ^ 1];
      load_lds16(kg,      Kd + lbase);
      load_lds16(kg + 32, Kd + 2048 + lbase);
      load_lds16(vg,      Vd + lbase);
      load_lds16(vg + 32, Vd + 2048 + lbase);
    }

    const bool diag = (it == qcur);
    const bf16_t* Kbuf = Ks[buf];

    // QK^T with permuted rows + softmax -> pf0/pf1 entirely in registers.
    // MFMA #i covers keys 8*quad + (i&1)*4 + r  [+32 for i>=2].
    bf16x8 pf0, pf1;
    #pragma unroll
    for (int i = 0; i < 4; ++i) {
      const int row = fr + (i & 1) * 4 + (i >> 1) * 32;
      bf16x8 ka = *(const bf16x8*)(Kbuf + row * 32 + quad * 8);
      bf16x8 kb = *(const bf16x8*)(Kbuf + 2048 + row * 32 + quad * 8);
      f32x4 s = {};
      s = mfma_bf16(ka, q0, s);
      s = mfma_bf16(kb, q1, s);
      const int kbase = (i >> 1) * 32 + quad * 8 + (i & 1) * 4;
      #pragma unroll
      for (int r = 0; r < 4; ++r) {
        float p = (!diag || (kbase + r <= lim)) ? __builtin_amdgcn_exp2f(s[r]) : 0.0f;
        lsum += p;
        const bf16_t pb = (bf16_t)p;
        if (i & 2) pf1[(i & 1) * 4 + r] = pb;
        else       pf0[(i & 1) * 4 + r] = pb;
      }
    }

    // PV: o[d][q] += V' * P   (pf0 = keys 0..31, pf1 = keys 32..63)
    const bf16_t* Vbuf = Vs[buf];
    #pragma unroll
    for (int dt = 0; dt < 4; ++dt) {
      bf16x8 va = *(const bf16x8*)(Vbuf + (16 * dt + col) * 32 + quad * 8);
      bf16x8 vb = *(const bf16x8*)(Vbuf + 2048 + (16 * dt + col) * 32 + quad * 8);
      o[dt] = mfma_bf16(va, pf0, o[dt]);
      o[dt] = mfma_bf16(vb, pf1, o[dt]);
    }

    if (diag) {
      // finalize current phase: reduce lsum across quads, normalize, store
      float ls = lsum;
      ls += __shfl_xor(ls, 16, 64);
      ls += __shfl_xor(ls, 32, 64);
      const float inv = 1.0f / ls;
      const int q = qcur * 64 + wave * 16 + col;
      const size_t orow = (size_t)(b * SEQ + q) * DMODEL + h * DH;
      #pragma unroll
      for (int dt = 0; dt < 4; ++dt) {
        bf16x4 v4 = { (bf16_t)(o[dt][0] * inv), (bf16_t)(o[dt][1] * inv),
                      (bf16_t)(o[dt][2] * inv), (bf16_t)(o[dt][3] * inv) };
        *(bf16x4*)(attn + orow + dt * 16 + quad * 4) = v4;
      }
      // switch to phase B
      #pragma unroll
      for (int dt = 0; dt < 4; ++dt) o[dt] = f32x4{};
      lsum = 0.0f;
      q0 = qfB0; q1 = qfB1;
      qcur = qtB;
      it = 0;
    } else {
      ++it;
    }
  }
}

// ---------------- Output projection (-> f32 d_out) ----------------
__global__ __launch_bounds__(256) void out_gemm_kernel(
    const bf16_t* __restrict__ Ab, const bf16_t* __restrict__ Wob,
    float* __restrict__ out)
{
  __shared__ __align__(16) bf16_t As[128 * 32];
  __shared__ __align__(16) bf16_t Bs[128 * 32];
  f32x4 acc[4][4] = {};
  const int m0 = blockIdx.x * 128;
  const int n0 = blockIdx.y * 128;
  gemm128(Ab + (size_t)m0 * DMODEL, Wob + (size_t)n0 * DMODEL, As, Bs, acc);

  const int t = threadIdx.x;
  const int lane = t & 63, w = t >> 6;
  const int col = lane & 15, quad = lane >> 4;
  const int wm = w >> 1, wn = w & 1;
  const int mbase = m0 + wm * 64;
  const int nbase = n0 + wn * 64;

  #pragma unroll
  for (int mt = 0; mt < 4; ++mt)
    #pragma unroll
    for (int nt = 0; nt < 4; ++nt)
      #pragma unroll
      for (int r = 0; r < 4; ++r)
        out[(size_t)(mbase + mt * 16 + quad * 4 + r) * DMODEL + nbase + nt * 16 + col] =
            acc[mt][nt][r];
}

extern "C" void kernel_launch(void* const* d_in, const int* in_sizes, int n_in,
                              void* d_out, int out_size, void* d_ws, size_t ws_size,
                              hipStream_t stream)
{
  (void)in_sizes; (void)n_in; (void)out_size; (void)ws_size;
  const float* x  = (const float*)d_in[0];
  const float* Wq = (const float*)d_in[1];
  const float* Wk = (const float*)d_in[2];
  const float* Wv = (const float*)d_in[3];
  const float* Wo = (const float*)d_in[4];
  const int* tpos = (const int*)d_in[5];
  float* out = (float*)d_out;

  const size_t M1 = (size_t)1024 * 1024;
  bf16_t* xb    = (bf16_t*)d_ws;                  // 4M elems
  bf16_t* Wall  = xb + 4 * M1;                    // Wq|Wk|Wv (3M)
  bf16_t* Wob   = xb + 7 * M1;                    // 1M
  bf16_t* Qb    = xb + 8 * M1;                    // 4M  (b,h,s,d)
  bf16_t* Kb    = Qb + 4 * M1;                    // 4M  (b,h,s,d)
  bf16_t* Vt    = Kb + 4 * M1;                    // 4M  (b,h,d,s)
  bf16_t* attnb = Vt + 4 * M1;                    // 4M  (b*s, h*d)

  convert_kernel<<<dim3(4096, 1, 1), dim3(256, 1, 1), 0, stream>>>(
      x, Wq, Wk, Wv, Wo, xb);
  qkv_gemm_kernel<<<dim3(32, 24, 1), dim3(256, 1, 1), 0, stream>>>(
      xb, Wall, Qb, Kb, Vt);
  rope_kernel<<<dim3(8192, 1, 1), dim3(256, 1, 1), 0, stream>>>(Qb, Kb, tpos);
  attn_kernel<<<dim3(32, 16, 1), dim3(256, 1, 1), 0, stream>>>(
      Qb, Kb, Vt, attnb);
  out_gemm_kernel<<<dim3(32, 8, 1), dim3(256, 1, 1), 0, stream>>>(
      attnb, Wob, out);
}